// Round 9
// baseline (2450.022 us; speedup 1.0000x reference)
//
#include <hip/hip_runtime.h>
#include <math.h>

// Shapes (fixed by the problem)
constexpr int TOK   = 1024 * 2048;           // B*S tokens
constexpr int TPB   = 256;
constexpr int NBLK  = 2048;
constexpr int ITERS = TOK / (NBLK * TPB);    // 4 tokens per thread

typedef float  f32x4 __attribute__((ext_vector_type(4)));
typedef __fp16 h2    __attribute__((ext_vector_type(2)));

// ws word layout (u32 words; f32 bit-pattern for the fp32 region):
// [0,32)     Gf[k=4][j=8]  f32   = embed_w^T @ gate_w
// [32,40)    gb[8]         f32   = embed_b @ gate_w
// [40,44)    pb[4]         f32
// [44,556)   hWf[e][f=32][p=2]   f16x2 {Wf[2p][f],Wf[2p+1][f]}
// [556,684)  hUb[e][j=16]        f16x2 {ub[2j],ub[2j+1]}
// [684,1196) hPf[e][j=16][o=4]   f16x2 {Pf[2j][o],Pf[2j+1][o]}
// [1196,1207) sigmoid poly coeffs c[11] (f32, odd monomials in x=z/8)
constexpr int OFF_GF = 0, OFF_GB = 32, OFF_PB = 40;
constexpr int OFF_WF = 44, OFF_UB = 556, OFF_PF = 684, WS_W = 1196;
constexpr int OFF_PC = 1196;
// LDS expert strides padded (stride % 32 == 4 words) like R0/R1 (0 conflicts).
constexpr int WF_S = 68, UB_S = 20, PF_S = 68;

__device__ __forceinline__ unsigned pk16(float a, float b) {
    unsigned ua = (unsigned)__builtin_bit_cast(unsigned short, (__fp16)a);
    unsigned ub = (unsigned)__builtin_bit_cast(unsigned short, (__fp16)b);
    return ua | (ub << 16);
}

__global__ void setup_fused(
    const float* __restrict__ ew,  // [16][4]
    const float* __restrict__ eb,  // [16]
    const float* __restrict__ gw,  // [16][8]
    const float* __restrict__ wi,  // [8][16][32]
    const float* __restrict__ wo,  // [8][32][16]
    const float* __restrict__ pw,  // [4][16]
    const float* __restrict__ pb,  // [4]
    unsigned* __restrict__ wsu)
{
    int idx = blockIdx.x * blockDim.x + threadIdx.x;
    if (idx >= WS_W) return;
    float* wsf = (float*)wsu;
    if (idx < OFF_GB) {
        int k = idx >> 3, j = idx & 7;
        float v = 0.f;
        for (int i = 0; i < 16; ++i) v += ew[i * 4 + k] * gw[i * 8 + j];
        wsf[idx] = v;
    } else if (idx < OFF_PB) {
        int j = idx - OFF_GB;
        float v = 0.f;
        for (int i = 0; i < 16; ++i) v += eb[i] * gw[i * 8 + j];
        wsf[idx] = v;
    } else if (idx < OFF_WF) {
        wsf[idx] = pb[idx - OFF_PB];
    } else if (idx < OFF_UB) {
        int r = idx - OFF_WF; int e = r >> 6, t = r & 63, f = t >> 1, p = t & 1;
        float v0 = 0.f, v1 = 0.f;
        for (int i = 0; i < 16; ++i) {
            float w = wi[(e * 16 + i) * 32 + f];
            v0 += ew[i * 4 + 2 * p]     * w;
            v1 += ew[i * 4 + 2 * p + 1] * w;
        }
        wsu[idx] = pk16(v0, v1);
    } else if (idx < OFF_PF) {
        int r = idx - OFF_UB; int e = r >> 4, j = r & 15;
        float v0 = 0.f, v1 = 0.f;
        for (int i = 0; i < 16; ++i) {
            v0 += eb[i] * wi[(e * 16 + i) * 32 + 2 * j];
            v1 += eb[i] * wi[(e * 16 + i) * 32 + 2 * j + 1];
        }
        wsu[idx] = pk16(v0, v1);
    } else {
        int r = idx - OFF_PF; int e = r >> 6, t = r & 63, j = t >> 2, o = t & 3;
        float v0 = 0.f, v1 = 0.f;
        for (int i = 0; i < 16; ++i) {
            float p = pw[o * 16 + i];
            v0 += wo[(e * 32 + 2 * j)     * 16 + i] * p;
            v1 += wo[(e * 32 + 2 * j + 1) * 16 + i] * p;
        }
        wsu[idx] = pk16(v0, v1);
    }
}

// Device-side Chebyshev projection (f64): sigma(8x)-0.5 ~ sum_{k odd<=21} b_k T_k(x).
// Exact discrete orthogonality at Chebyshev nodes; converts to monomials via
// the T-recurrence. No memorized minimax constants, no linear solve.
__global__ void fit_sig(float* __restrict__ cws) {
    if (threadIdx.x != 0 || blockIdx.x != 0) return;
    const int N = 1024;
    const int KD = 21;
    double b[KD + 1];
    for (int k = 0; k <= KD; ++k) b[k] = 0.0;
    for (int n = 0; n < N; ++n) {
        double th = M_PI * (n + 0.5) / N;
        double z  = 8.0 * cos(th);
        double f  = 1.0 / (1.0 + exp(-z)) - 0.5;
        for (int k = 1; k <= KD; k += 2) b[k] += f * cos(k * th);
    }
    for (int k = 1; k <= KD; k += 2) b[k] *= 2.0 / N;
    double Tm1[KD + 1], T0m[KD + 1], cm[KD + 1], Tn[KD + 1];
    for (int j = 0; j <= KD; ++j) { Tm1[j] = 0.0; T0m[j] = 0.0; cm[j] = 0.0; }
    Tm1[0] = 1.0;   // T_0 = 1
    T0m[1] = 1.0;   // T_1 = x
    for (int j = 0; j <= KD; ++j) cm[j] += b[1] * T0m[j];
    for (int k = 2; k <= KD; ++k) {
        for (int j = 0; j <= KD; ++j) Tn[j] = -Tm1[j];
        for (int j = 0; j <  KD; ++j) Tn[j + 1] += 2.0 * T0m[j];
        if (k & 1)
            for (int j = 0; j <= KD; ++j) cm[j] += b[k] * Tn[j];
        for (int j = 0; j <= KD; ++j) { Tm1[j] = T0m[j]; T0m[j] = Tn[j]; }
    }
    for (int i = 0; i <= 10; ++i) cws[i] = (float)cm[2 * i + 1];
}

__device__ __forceinline__ f32x4 splat4(float s) { return (f32x4){s, s, s, s}; }
__device__ __forceinline__ h2 bch2(unsigned u) { return __builtin_bit_cast(h2, u); }

__global__ __launch_bounds__(256) void moe_main(
    const float* __restrict__ x,      // [T][4]
    const unsigned* __restrict__ wsu, // fused weights
    float* __restrict__ out)          // [T][4]
{
    __shared__ __align__(16) unsigned sWf[8 * WF_S];
    __shared__ __align__(16) unsigned sUb[8 * UB_S];
    __shared__ __align__(16) unsigned sPf[8 * PF_S];

    const float* wsf = (const float*)wsu;
    const int tid = threadIdx.x;

    for (int i = tid; i < 512; i += TPB) {
        int e = i >> 6, r = i & 63;
        sWf[e * WF_S + r] = wsu[OFF_WF + i];
        sPf[e * PF_S + r] = wsu[OFF_PF + i];
    }
    if (tid < 128) {
        int e = tid >> 4, r = tid & 15;
        sUb[e * UB_S + r] = wsu[OFF_UB + tid];
    }

    const f32x4* __restrict__ x4 = (const f32x4*)x;
    f32x4* __restrict__ o4       = (f32x4*)out;

    // Wave-uniform gate/proj params + sigmoid poly coeffs (broadcast loads).
    f32x4 Gr[8];
    #pragma unroll
    for (int q = 0; q < 8; ++q) Gr[q] = ((const f32x4*)wsf)[q];
    const f32x4 w_gb0 = ((const f32x4*)wsf)[8];
    const f32x4 w_gb1 = ((const f32x4*)wsf)[9];
    const f32x4 w_pb  = *(const f32x4*)(wsf + OFF_PB);
    float pc[11];
    #pragma unroll
    for (int q = 0; q < 11; ++q) pc[q] = wsf[OFF_PC + q];

    constexpr float LOG2E  = 1.4426950408889634f;
    constexpr float GELU_B = 0.044715f;
    constexpr float ZSCALE = 0.19947114025f;  // 2*0.7978845608/8 : x = z/8
    const f32x4 one4 = splat4(1.0f);

    __syncthreads();

    int t = blockIdx.x * TPB + tid;
    #pragma unroll 2
    for (int it = 0; it < ITERS; ++it, t += NBLK * TPB) {
        f32x4 xv = x4[t];

        // --- gate logits (f32, identical math to R1 -> routing unchanged) ---
        f32x4 ga = w_gb0, gb2 = w_gb1;
        #pragma unroll
        for (int k = 0; k < 4; ++k) {
            f32x4 xs = splat4(xv[k]);
            ga  = __builtin_elementwise_fma(xs, Gr[2 * k],     ga);
            gb2 = __builtin_elementwise_fma(xs, Gr[2 * k + 1], gb2);
        }
        float g[8] = {ga[0], ga[1], ga[2], ga[3], gb2[0], gb2[1], gb2[2], gb2[3]};

        float gmax = g[0]; int e = 0;
        #pragma unroll
        for (int j = 1; j < 8; ++j)
            if (g[j] > gmax) { gmax = g[j]; e = j; }
        float ssum = 0.0f;
        #pragma unroll
        for (int j = 0; j < 8; ++j)
            ssum += __builtin_amdgcn_exp2f((g[j] - gmax) * LOG2E);
        float tp = __builtin_amdgcn_rcpf(ssum);

        // --- expert FFN in f16 (dot2, f32 accumulate) ---
        h2 x01 = __builtin_amdgcn_cvt_pkrtz(xv[0], xv[1]);
        h2 x23 = __builtin_amdgcn_cvt_pkrtz(xv[2], xv[3]);

        const uint4* __restrict__ wf4 = (const uint4*)(sWf + e * WF_S);
        const uint4* __restrict__ ub4 = (const uint4*)(sUb + e * UB_S);
        const uint4* __restrict__ pf4 = (const uint4*)(sPf + e * PF_S);

        uint4 ubv0 = ub4[0], ubv1 = ub4[1], ubv2 = ub4[2], ubv3 = ub4[3];
        unsigned ubw[16] = {ubv0.x, ubv0.y, ubv0.z, ubv0.w,
                            ubv1.x, ubv1.y, ubv1.z, ubv1.w,
                            ubv2.x, ubv2.y, ubv2.z, ubv2.w,
                            ubv3.x, ubv3.y, ubv3.z, ubv3.w};

        f32x4 Ug[8];
        #pragma unroll
        for (int j = 0; j < 8; ++j) {           // f = 4j .. 4j+3
            uint4 wa = wf4[2 * j];
            uint4 wb = wf4[2 * j + 1];
            h2 hb0 = bch2(ubw[2 * j]);
            h2 hb1 = bch2(ubw[2 * j + 1]);
            f32x4 U;
            U[0] = __builtin_amdgcn_fdot2(x01, bch2(wa.x),
                     __builtin_amdgcn_fdot2(x23, bch2(wa.y), (float)hb0.x, false), false);
            U[1] = __builtin_amdgcn_fdot2(x01, bch2(wa.z),
                     __builtin_amdgcn_fdot2(x23, bch2(wa.w), (float)hb0.y, false), false);
            U[2] = __builtin_amdgcn_fdot2(x01, bch2(wb.x),
                     __builtin_amdgcn_fdot2(x23, bch2(wb.y), (float)hb1.x, false), false);
            U[3] = __builtin_amdgcn_fdot2(x01, bch2(wb.z),
                     __builtin_amdgcn_fdot2(x23, bch2(wb.w), (float)hb1.y, false), false);
            Ug[j] = U;
        }

        // --- gelu via odd-poly sigmoid: gelu = v * s, s = 0.5 + x*P(x^2),
        //     x = clamp(z/8), z = 1.59577*(v + 0.044715 v^3). Zero trans ops. ---
        #pragma unroll
        for (int j = 0; j < 8; ++j) {
            f32x4 vv = Ug[j];
            f32x4 wv = vv * vv;
            f32x4 mm = __builtin_elementwise_fma(splat4(GELU_B), wv, one4);
            f32x4 xz = (vv * mm) * splat4(ZSCALE);
            xz = __builtin_elementwise_min(
                     __builtin_elementwise_max(xz, splat4(-1.0f)), one4);
            f32x4 xw = xz * xz;
            f32x4 P  = splat4(pc[10]);
            #pragma unroll
            for (int q = 9; q >= 0; --q)
                P = __builtin_elementwise_fma(xw, P, splat4(pc[q]));
            f32x4 s = __builtin_elementwise_fma(xz, P, splat4(0.5f));
            s = __builtin_elementwise_min(
                    __builtin_elementwise_max(s, splat4(0.0f)), one4);
            Ug[j] = vv * s;
        }

        // --- PV: acc_o = sum_f gelu(U)_f * Pf[f][o]  (f16 pairs, f32 acc) ---
        f32x4 acc = splat4(0.0f);
        #pragma unroll
        for (int j = 0; j < 8; ++j) {
            h2 a01 = __builtin_amdgcn_cvt_pkrtz(Ug[j][0], Ug[j][1]);
            h2 a23 = __builtin_amdgcn_cvt_pkrtz(Ug[j][2], Ug[j][3]);
            uint4 p0 = pf4[2 * j];
            uint4 p1 = pf4[2 * j + 1];
            acc[0] = __builtin_amdgcn_fdot2(a01, bch2(p0.x), acc[0], false);
            acc[1] = __builtin_amdgcn_fdot2(a01, bch2(p0.y), acc[1], false);
            acc[2] = __builtin_amdgcn_fdot2(a01, bch2(p0.z), acc[2], false);
            acc[3] = __builtin_amdgcn_fdot2(a01, bch2(p0.w), acc[3], false);
            acc[0] = __builtin_amdgcn_fdot2(a23, bch2(p1.x), acc[0], false);
            acc[1] = __builtin_amdgcn_fdot2(a23, bch2(p1.y), acc[1], false);
            acc[2] = __builtin_amdgcn_fdot2(a23, bch2(p1.z), acc[2], false);
            acc[3] = __builtin_amdgcn_fdot2(a23, bch2(p1.w), acc[3], false);
        }

        o4[t] = __builtin_elementwise_fma(splat4(tp), acc, w_pb);
    }
}

extern "C" void kernel_launch(void* const* d_in, const int* in_sizes, int n_in,
                              void* d_out, int out_size, void* d_ws, size_t ws_size,
                              hipStream_t stream) {
    const float* x  = (const float*)d_in[0];
    const float* ew = (const float*)d_in[1];
    const float* eb = (const float*)d_in[2];
    const float* gw = (const float*)d_in[3];
    const float* wi = (const float*)d_in[4];
    const float* wo = (const float*)d_in[5];
    const float* pw = (const float*)d_in[6];
    const float* pb = (const float*)d_in[7];
    unsigned* wsu = (unsigned*)d_ws;
    float* out    = (float*)d_out;

    setup_fused<<<(WS_W + 255) / 256, 256, 0, stream>>>(ew, eb, gw, wi, wo, pw, pb, wsu);
    fit_sig<<<1, 64, 0, stream>>>((float*)(wsu + OFF_PC));
    moe_main<<<NBLK, TPB, 0, stream>>>(x, wsu, out);
}

// Round 10
// 51.342 us; speedup vs baseline: 47.7193x; 47.7193x over previous
//
#include <hip/hip_runtime.h>

// Shapes (fixed by the problem)
constexpr int TOK   = 1024 * 2048;           // B*S tokens
constexpr int TPB   = 256;
constexpr int NBLK  = 2048;
constexpr int ITERS = TOK / (NBLK * TPB);    // 4 tokens per thread

typedef float  f32x4 __attribute__((ext_vector_type(4)));
typedef __fp16 h2    __attribute__((ext_vector_type(2)));

// ws word layout (u32 words; f32 bit-pattern for the fp32 region):
// [0,32)     Gf[k=4][j=8]  f32   = embed_w^T @ gate_w
// [32,40)    gb[8]         f32   = embed_b @ gate_w
// [40,44)    pb[4]         f32
// [44,556)   hWf[e][f=32][p=2]   f16x2 {Wf[2p][f],Wf[2p+1][f]}
// [556,684)  hUb[e][j=16]        f16x2 {ub[2j],ub[2j+1]}
// [684,1196) hPf[e][j=16][o=4]   f16x2 {Pf[2j][o],Pf[2j+1][o]}
constexpr int OFF_GF = 0, OFF_GB = 32, OFF_PB = 40;
constexpr int OFF_WF = 44, OFF_UB = 556, OFF_PF = 684, WS_W = 1196;
// LDS expert strides padded (stride % 32 == 4 words) like R0/R1 (0 conflicts).
constexpr int WF_S = 68, UB_S = 20, PF_S = 68;

// ---------------- compile-time Chebyshev fit of sigmoid ----------------
// sigma(8x)-0.5 ≈ sum_{k odd<=21} b_k T_k(x) on x in [-1,1], converted to
// odd monomial coeffs. All evaluated by the compiler -> literals in-kernel.
constexpr double cexp_pos(double x) {   // x >= 0
    int k = 0;
    while (x > 0.5) { x *= 0.5; ++k; }
    double s = 1.0, term = 1.0;
    for (int i = 1; i < 30; ++i) { term *= x / i; s += term; }
    for (int i = 0; i < k; ++i) s *= s;
    return s;
}
constexpr double cexp(double x) { return x < 0 ? 1.0 / cexp_pos(-x) : cexp_pos(x); }
constexpr double ccos(double x) {       // adequate for x in [0, pi]
    double x2 = x * x, s = 1.0, term = 1.0;
    for (int i = 1; i < 26; ++i) { term *= -x2 / ((2.0 * i - 1.0) * (2.0 * i)); s += term; }
    return s;
}
struct Coef { double c[11]; };
constexpr Coef fit_sig() {
    const int N = 256, KD = 21;
    const double PI = 3.14159265358979323846;
    double b[KD + 1] = {};
    for (int n = 0; n < N; ++n) {
        double th = PI * (n + 0.5) / N;
        double ct = ccos(th);
        double f  = 1.0 / (1.0 + cexp(-8.0 * ct)) - 0.5;
        double cm1 = 1.0, c0 = ct;          // cos(0*th), cos(1*th)
        b[1] += f * c0;
        for (int k = 2; k <= KD; ++k) {
            double ck = 2.0 * ct * c0 - cm1;
            cm1 = c0; c0 = ck;
            if (k & 1) b[k] += f * ck;
        }
    }
    for (int k = 1; k <= KD; k += 2) b[k] *= 2.0 / N;
    double Tm1[KD + 1] = {}, T0m[KD + 1] = {}, cmo[KD + 1] = {}, Tn[KD + 1] = {};
    Tm1[0] = 1.0; T0m[1] = 1.0;
    for (int j = 0; j <= KD; ++j) cmo[j] += b[1] * T0m[j];
    for (int k = 2; k <= KD; ++k) {
        for (int j = 0; j <= KD; ++j) Tn[j] = -Tm1[j];
        for (int j = 0; j <  KD; ++j) Tn[j + 1] += 2.0 * T0m[j];
        if (k & 1)
            for (int j = 0; j <= KD; ++j) cmo[j] += b[k] * Tn[j];
        for (int j = 0; j <= KD; ++j) { Tm1[j] = T0m[j]; T0m[j] = Tn[j]; }
    }
    Coef r{};
    for (int i = 0; i <= 10; ++i) r.c[i] = cmo[2 * i + 1];
    return r;
}
constexpr Coef PC = fit_sig();

__device__ __forceinline__ unsigned pk16(float a, float b) {
    unsigned ua = (unsigned)__builtin_bit_cast(unsigned short, (__fp16)a);
    unsigned ub = (unsigned)__builtin_bit_cast(unsigned short, (__fp16)b);
    return ua | (ub << 16);
}

__global__ void setup_fused(
    const float* __restrict__ ew,  // [16][4]
    const float* __restrict__ eb,  // [16]
    const float* __restrict__ gw,  // [16][8]
    const float* __restrict__ wi,  // [8][16][32]
    const float* __restrict__ wo,  // [8][32][16]
    const float* __restrict__ pw,  // [4][16]
    const float* __restrict__ pb,  // [4]
    unsigned* __restrict__ wsu)
{
    int idx = blockIdx.x * blockDim.x + threadIdx.x;
    if (idx >= WS_W) return;
    float* wsf = (float*)wsu;
    if (idx < OFF_GB) {
        int k = idx >> 3, j = idx & 7;
        float v = 0.f;
        for (int i = 0; i < 16; ++i) v += ew[i * 4 + k] * gw[i * 8 + j];
        wsf[idx] = v;
    } else if (idx < OFF_PB) {
        int j = idx - OFF_GB;
        float v = 0.f;
        for (int i = 0; i < 16; ++i) v += eb[i] * gw[i * 8 + j];
        wsf[idx] = v;
    } else if (idx < OFF_WF) {
        wsf[idx] = pb[idx - OFF_PB];
    } else if (idx < OFF_UB) {
        int r = idx - OFF_WF; int e = r >> 6, t = r & 63, f = t >> 1, p = t & 1;
        float v0 = 0.f, v1 = 0.f;
        for (int i = 0; i < 16; ++i) {
            float w = wi[(e * 16 + i) * 32 + f];
            v0 += ew[i * 4 + 2 * p]     * w;
            v1 += ew[i * 4 + 2 * p + 1] * w;
        }
        wsu[idx] = pk16(v0, v1);
    } else if (idx < OFF_PF) {
        int r = idx - OFF_UB; int e = r >> 4, j = r & 15;
        float v0 = 0.f, v1 = 0.f;
        for (int i = 0; i < 16; ++i) {
            v0 += eb[i] * wi[(e * 16 + i) * 32 + 2 * j];
            v1 += eb[i] * wi[(e * 16 + i) * 32 + 2 * j + 1];
        }
        wsu[idx] = pk16(v0, v1);
    } else {
        int r = idx - OFF_PF; int e = r >> 6, t = r & 63, j = t >> 2, o = t & 3;
        float v0 = 0.f, v1 = 0.f;
        for (int i = 0; i < 16; ++i) {
            float p = pw[o * 16 + i];
            v0 += wo[(e * 32 + 2 * j)     * 16 + i] * p;
            v1 += wo[(e * 32 + 2 * j + 1) * 16 + i] * p;
        }
        wsu[idx] = pk16(v0, v1);
    }
}

__device__ __forceinline__ f32x4 splat4(float s) { return (f32x4){s, s, s, s}; }
__device__ __forceinline__ h2 bch2(unsigned u) { return __builtin_bit_cast(h2, u); }

__global__ __launch_bounds__(256) void moe_main(
    const float* __restrict__ x,      // [T][4]
    const unsigned* __restrict__ wsu, // fused weights
    float* __restrict__ out)          // [T][4]
{
    __shared__ __align__(16) unsigned sWf[8 * WF_S];
    __shared__ __align__(16) unsigned sUb[8 * UB_S];
    __shared__ __align__(16) unsigned sPf[8 * PF_S];

    const float* wsf = (const float*)wsu;
    const int tid = threadIdx.x;

    for (int i = tid; i < 512; i += TPB) {
        int e = i >> 6, r = i & 63;
        sWf[e * WF_S + r] = wsu[OFF_WF + i];
        sPf[e * PF_S + r] = wsu[OFF_PF + i];
    }
    if (tid < 128) {
        int e = tid >> 4, r = tid & 15;
        sUb[e * UB_S + r] = wsu[OFF_UB + tid];
    }

    const f32x4* __restrict__ x4 = (const f32x4*)x;
    f32x4* __restrict__ o4       = (f32x4*)out;

    // Wave-uniform gate/proj params (broadcast f32 loads from global).
    f32x4 Gr[8];
    #pragma unroll
    for (int q = 0; q < 8; ++q) Gr[q] = ((const f32x4*)wsf)[q];
    const f32x4 w_gb0 = ((const f32x4*)wsf)[8];
    const f32x4 w_gb1 = ((const f32x4*)wsf)[9];
    const f32x4 w_pb  = *(const f32x4*)(wsf + OFF_PB);

    constexpr float LOG2E  = 1.4426950408889634f;
    constexpr float GELU_B = 0.044715f;
    constexpr float ZSCALE = 0.19947114025f;  // 2*0.7978845608/8 : x = z/8
    const f32x4 one4 = splat4(1.0f);

    __syncthreads();

    int t = blockIdx.x * TPB + tid;
    #pragma unroll 2
    for (int it = 0; it < ITERS; ++it, t += NBLK * TPB) {
        f32x4 xv = x4[t];

        // --- gate logits (f32, identical math to R1 -> routing unchanged) ---
        f32x4 ga = w_gb0, gb2 = w_gb1;
        #pragma unroll
        for (int k = 0; k < 4; ++k) {
            f32x4 xs = splat4(xv[k]);
            ga  = __builtin_elementwise_fma(xs, Gr[2 * k],     ga);
            gb2 = __builtin_elementwise_fma(xs, Gr[2 * k + 1], gb2);
        }
        float g[8] = {ga[0], ga[1], ga[2], ga[3], gb2[0], gb2[1], gb2[2], gb2[3]};

        float gmax = g[0]; int e = 0;
        #pragma unroll
        for (int j = 1; j < 8; ++j)
            if (g[j] > gmax) { gmax = g[j]; e = j; }
        float ssum = 0.0f;
        #pragma unroll
        for (int j = 0; j < 8; ++j)
            ssum += __builtin_amdgcn_exp2f((g[j] - gmax) * LOG2E);
        float tp = __builtin_amdgcn_rcpf(ssum);

        // --- expert FFN in f16 (dot2, f32 accumulate) ---
        h2 x01 = __builtin_amdgcn_cvt_pkrtz(xv[0], xv[1]);
        h2 x23 = __builtin_amdgcn_cvt_pkrtz(xv[2], xv[3]);

        const uint4* __restrict__ wf4 = (const uint4*)(sWf + e * WF_S);
        const uint4* __restrict__ ub4 = (const uint4*)(sUb + e * UB_S);
        const uint4* __restrict__ pf4 = (const uint4*)(sPf + e * PF_S);

        uint4 ubv0 = ub4[0], ubv1 = ub4[1], ubv2 = ub4[2], ubv3 = ub4[3];
        unsigned ubw[16] = {ubv0.x, ubv0.y, ubv0.z, ubv0.w,
                            ubv1.x, ubv1.y, ubv1.z, ubv1.w,
                            ubv2.x, ubv2.y, ubv2.z, ubv2.w,
                            ubv3.x, ubv3.y, ubv3.z, ubv3.w};

        f32x4 Ug[8];
        #pragma unroll
        for (int j = 0; j < 8; ++j) {           // f = 4j .. 4j+3
            uint4 wa = wf4[2 * j];
            uint4 wb = wf4[2 * j + 1];
            h2 hb0 = bch2(ubw[2 * j]);
            h2 hb1 = bch2(ubw[2 * j + 1]);
            f32x4 U;
            U[0] = __builtin_amdgcn_fdot2(x01, bch2(wa.x),
                     __builtin_amdgcn_fdot2(x23, bch2(wa.y), (float)hb0.x, false), false);
            U[1] = __builtin_amdgcn_fdot2(x01, bch2(wa.z),
                     __builtin_amdgcn_fdot2(x23, bch2(wa.w), (float)hb0.y, false), false);
            U[2] = __builtin_amdgcn_fdot2(x01, bch2(wb.x),
                     __builtin_amdgcn_fdot2(x23, bch2(wb.y), (float)hb1.x, false), false);
            U[3] = __builtin_amdgcn_fdot2(x01, bch2(wb.z),
                     __builtin_amdgcn_fdot2(x23, bch2(wb.w), (float)hb1.y, false), false);
            Ug[j] = U;
        }

        // --- gelu via odd-poly sigmoid: gelu = v*s, s = 0.5 + x*P(x^2),
        //     x = clamp(z/8), z = 1.59577*(v + 0.044715 v^3). Zero trans ops. ---
        #pragma unroll
        for (int j = 0; j < 8; ++j) {
            f32x4 vv = Ug[j];
            f32x4 wv = vv * vv;
            f32x4 mm = __builtin_elementwise_fma(splat4(GELU_B), wv, one4);
            f32x4 xz = (vv * mm) * splat4(ZSCALE);
            xz = __builtin_elementwise_min(
                     __builtin_elementwise_max(xz, splat4(-1.0f)), one4);
            f32x4 xw = xz * xz;
            f32x4 P  = splat4((float)PC.c[10]);
            #pragma unroll
            for (int q = 9; q >= 0; --q)
                P = __builtin_elementwise_fma(xw, P, splat4((float)PC.c[q]));
            f32x4 s = __builtin_elementwise_fma(xz, P, splat4(0.5f));
            s = __builtin_elementwise_min(
                    __builtin_elementwise_max(s, splat4(0.0f)), one4);
            Ug[j] = vv * s;
        }

        // --- PV: acc_o = sum_f gelu(U)_f * Pf[f][o]  (f16 pairs, f32 acc) ---
        f32x4 acc = splat4(0.0f);
        #pragma unroll
        for (int j = 0; j < 8; ++j) {
            h2 a01 = __builtin_amdgcn_cvt_pkrtz(Ug[j][0], Ug[j][1]);
            h2 a23 = __builtin_amdgcn_cvt_pkrtz(Ug[j][2], Ug[j][3]);
            uint4 p0 = pf4[2 * j];
            uint4 p1 = pf4[2 * j + 1];
            acc[0] = __builtin_amdgcn_fdot2(a01, bch2(p0.x), acc[0], false);
            acc[1] = __builtin_amdgcn_fdot2(a01, bch2(p0.y), acc[1], false);
            acc[2] = __builtin_amdgcn_fdot2(a01, bch2(p0.z), acc[2], false);
            acc[3] = __builtin_amdgcn_fdot2(a01, bch2(p0.w), acc[3], false);
            acc[0] = __builtin_amdgcn_fdot2(a23, bch2(p1.x), acc[0], false);
            acc[1] = __builtin_amdgcn_fdot2(a23, bch2(p1.y), acc[1], false);
            acc[2] = __builtin_amdgcn_fdot2(a23, bch2(p1.z), acc[2], false);
            acc[3] = __builtin_amdgcn_fdot2(a23, bch2(p1.w), acc[3], false);
        }

        o4[t] = __builtin_elementwise_fma(splat4(tp), acc, w_pb);
    }
}

extern "C" void kernel_launch(void* const* d_in, const int* in_sizes, int n_in,
                              void* d_out, int out_size, void* d_ws, size_t ws_size,
                              hipStream_t stream) {
    const float* x  = (const float*)d_in[0];
    const float* ew = (const float*)d_in[1];
    const float* eb = (const float*)d_in[2];
    const float* gw = (const float*)d_in[3];
    const float* wi = (const float*)d_in[4];
    const float* wo = (const float*)d_in[5];
    const float* pw = (const float*)d_in[6];
    const float* pb = (const float*)d_in[7];
    unsigned* wsu = (unsigned*)d_ws;
    float* out    = (float*)d_out;

    setup_fused<<<(WS_W + 255) / 256, 256, 0, stream>>>(ew, eb, gw, wi, wo, pw, pb, wsu);
    moe_main<<<NBLK, TPB, 0, stream>>>(x, wsu, out);
}